// Round 15
// baseline (239.907 us; speedup 1.0000x reference)
//
#include <hip/hip_runtime.h>
#include <stdint.h>

#define D_IN 1280
#define FROWS 4

typedef __attribute__((ext_vector_type(8))) short s16x8;
typedef __attribute__((ext_vector_type(4))) float f32x4;
typedef __attribute__((ext_vector_type(16))) float f32x16;
typedef __attribute__((ext_vector_type(4))) unsigned int u32x4;

__device__ __forceinline__ unsigned short f2bf(float f) {
  union { float f; unsigned u; } v;
  v.f = f;
  unsigned u = v.u;
  return (unsigned short)((u + 0x7fffu + ((u >> 16) & 1u)) >> 16);  // RNE
}

__device__ __forceinline__ unsigned int cvtpk(float lo, float hi) {
  unsigned int r;
  asm("v_cvt_pk_bf16_f32 %0, %1, %2" : "=v"(r) : "v"(lo), "v"(hi));
  return r;
}

__device__ __forceinline__ void gload_lds16(const void* g, void* l) {
  __builtin_amdgcn_global_load_lds(
      (const __attribute__((address_space(1))) void*)g,
      (__attribute__((address_space(3))) void*)l, 16, 0, 0);
}

// ---------------- prep: fused {cayley+filt | cvt} (R11-verified) -----------
__global__ __launch_bounds__(320) void prep_kernel(
    const float* __restrict__ A1, const float* __restrict__ A2,
    const float* __restrict__ A3, const float* __restrict__ W,
    const float* __restrict__ x, unsigned short* __restrict__ filt,
    unsigned short* __restrict__ xb) {
  __shared__ __align__(16) char smem[69632];
  const int bid = blockIdx.x;
  const int t = threadIdx.x;

  if (bid >= 320) {
    const size_t stride = (size_t)2048 * 320 * 8;
    size_t i = ((size_t)(bid - 320) * 320 + t) * 8;
#pragma unroll
    for (int it = 0; it < 8; ++it, i += stride) {
      float4 a = *(const float4*)(x + i);
      float4 b = *(const float4*)(x + i + 4);
      u32x4 p;
      p[0] = cvtpk(a.x, a.y); p[1] = cvtpk(a.z, a.w);
      p[2] = cvtpk(b.x, b.y); p[3] = cvtpk(b.z, b.w);
      *(u32x4*)(xb + i) = p;
    }
    return;
  }

  float (*wS)[D_IN]  = (float (*)[D_IN])(smem);
  float (*t1S)[D_IN] = (float (*)[D_IN])(smem + 20480);
  float (*t2S)[D_IN] = (float (*)[D_IN])(smem + 40960);
  float (*augS)[80]  = (float (*)[80])(smem + 40960);
  float (*NmS)[40]   = (float (*)[40])(smem + 53760);
  float* facS        = (float*)(smem + 60160);
  float* q1S         = (float*)(smem + 61440);
  float* q2S         = (float*)(smem + 61504);
  float* q3S         = (float*)(smem + 61760);

  const int ob = bid * FROWS;

  for (int k = t; k < FROWS * 320; k += 320) {
    int r = k / 320, c = k % 320;
    ((float4*)wS[r])[c] = ((const float4*)(W + (size_t)(ob + r) * D_IN))[c];
  }

  for (int which = 0; which < 3; ++which) {
    const float* __restrict__ A = which == 0 ? A1 : (which == 1 ? A2 : A3);
    float* qd = which == 0 ? q1S : (which == 1 ? q2S : q3S);
    const int n = which == 0 ? 4 : (which == 1 ? 8 : 40);

    for (int idx = t; idx < n * n; idx += 320) {
      int i = idx / n, j = idx % n;
      float s = 0.5f * (A[i * n + j] - A[j * n + i]);
      float eye = (i == j) ? 1.0f : 0.0f;
      augS[i][j] = eye + s;
      augS[i][n + j] = eye;
      NmS[i][j] = eye - s;
    }
    __syncthreads();

    for (int p = 0; p < n; ++p) {
      const float dv = augS[p][p];
      if (t < n) facS[t] = (t == p) ? 0.0f : augS[t][p];
      __syncthreads();
      const float inv = 1.0f / dv;
      if (t < 2 * n) augS[p][t] *= inv;
      __syncthreads();
      for (int idx = t; idx < n * 2 * n; idx += 320) {
        int i = idx / (2 * n), j = idx % (2 * n);
        augS[i][j] -= facS[i] * augS[p][j];
      }
      __syncthreads();
    }

    for (int idx = t; idx < n * n; idx += 320) {
      int i = idx / n, j = idx % n;
      float acc = 0.0f;
      for (int k = 0; k < n; ++k) acc += NmS[i][k] * augS[k][n + j];
      qd[i * n + j] = acc;
    }
    __syncthreads();
  }

  const int i3 = t % 40;
  const int g = t / 40;  // 0..7
  float q3c[40];
#pragma unroll
  for (int j3 = 0; j3 < 40; ++j3) q3c[j3] = q3S[i3 * 40 + j3];
  __syncthreads();

#pragma unroll
  for (int kk = 0; kk < 16; ++kk) {
    const int item = g * 16 + kk;
    const int r = item >> 5;
    const int b = (item & 31) * 40;
    float s = 0.0f;
#pragma unroll
    for (int j3 = 0; j3 < 40; ++j3) s += wS[r][b + j3] * q3c[j3];
    t1S[r][b + i3] = s;
  }
  __syncthreads();

  for (int e = t; e < FROWS * D_IN; e += 320) {
    const int r = e / D_IN;
    const int i = e - r * D_IN;
    const int ii3 = i % 40;
    const int i2 = (i / 40) & 7;
    const int j1 = i / 320;
    float s = 0.0f;
#pragma unroll
    for (int j2 = 0; j2 < 8; ++j2) s += q2S[i2 * 8 + j2] * t1S[r][j1 * 320 + j2 * 40 + ii3];
    t2S[r][i] = s;
  }
  __syncthreads();

  for (int e = t; e < FROWS * D_IN; e += 320) {
    const int r = e / D_IN;
    const int i = e - r * D_IN;
    const int lo = i % 320;
    const int i1 = i / 320;
    float s = 0.0f;
#pragma unroll
    for (int j1 = 0; j1 < 4; ++j1) s += q1S[i1 * 4 + j1] * t2S[r][j1 * 320 + lo];
    filt[(size_t)(ob + r) * D_IN + i] = f2bf(s);
  }
}

// ---------------- main GEMM: 8-phase, 256x256, tri-buf B, 32x32x16 MFMA ----
// R14 base with ONE change: MFMA shape 16x16x32 -> 32x32x16 (4060 vs 3378
// FLOP/cyc; half the MFMA instruction count). Per-wave 128x64 = 4mf x 2nf
// frags of 32x32; K=64 = 4 kf of 16. A-frag: row=lane&31, k=(lane>>5)*8+e
// (K-doubling pattern, same family as the verified 16x16x32 mapping);
// C/D: col=lane&31, row=(reg&3)+8*(reg>>2)+4*(lane>>5) [m74/m101-verified].
// LDS slot = (kf*2 + (lane>>5)) ^ (lane&7) — consecutive 8-lane groups span
// 8 distinct phys slots (same conflict-free property as before). Staging,
// vmcnt counts, phase structure, swizzle all byte-identical to R14.
__global__ __launch_bounds__(512, 1) void gemm8p_kernel(
    const unsigned short* __restrict__ xb,
    const unsigned short* __restrict__ filt,
    float* __restrict__ out) {
  __shared__ short As[2][2][128][64];   // 64 KB
  __shared__ short Bs[3][2][128][64];   // 96 KB

  const int t = threadIdx.x;
  const int lane = t & 63;
  const int wave = t >> 6;
  const int wr = wave >> 2;          // 0..1: M half (128 rows)
  const int wc = wave & 3;           // 0..3: N slice (64 cols)
  const int hb = wc >> 1;            // B half
  const int nloc = (wc & 1) * 64;    // row base within B half

  const int nwg = gridDim.x;         // 640, % 8 == 0
  const int bid = blockIdx.x;
  const int wg = (bid & 7) * (nwg >> 3) + (bid >> 3);  // bijective XCD swizzle
  const int mt = wg / 5;
  const int nt = wg % 5;
  const int mbase = mt * 256;
  const int nbase = nt * 256;

  f32x16 acc[4][2];
#pragma unroll
  for (int mf = 0; mf < 4; ++mf)
#pragma unroll
    for (int nf = 0; nf < 2; ++nf) acc[mf][nf] = 0.0f;

  const int tr = t >> 3;                        // 0..63
  const int scol = (((t & 7) ^ (tr & 7)) << 3); // source col (elems)
  const int pslot = (t & 7) << 3;               // dest col (elems)
  const unsigned short* __restrict__ abase = xb + (size_t)mbase * D_IN + scol;
  const unsigned short* __restrict__ bbase = filt + (size_t)nbase * D_IN + scol;

#define STAGE_A(P, H, KT)                                                     \
  {                                                                           \
    _Pragma("unroll")                                                         \
    for (int q = 0; q < 2; ++q)                                               \
      gload_lds16(abase + (size_t)((H)*128 + q * 64 + tr) * D_IN + (KT)*64,   \
                  (void*)&As[P][H][q * 64 + tr][pslot]);                      \
  }
#define STAGE_B(P, H, KT)                                                     \
  {                                                                           \
    _Pragma("unroll")                                                         \
    for (int q = 0; q < 2; ++q)                                               \
      gload_lds16(bbase + (size_t)((H)*128 + q * 64 + tr) * D_IN + (KT)*64,   \
                  (void*)&Bs[P][H][q * 64 + tr][pslot]);                      \
  }

  const int l31 = lane & 31;
  const int l7 = lane & 7;
  const int ls = lane >> 5;          // 0..1: k-slot within kf
  // phys 16B-slot for k-frag kf: ((kf*2 + ls) ^ l7), row-stripe-invariant
  int kslot[4];
#pragma unroll
  for (int kf = 0; kf < 4; ++kf) kslot[kf] = (((kf * 2 + ls) ^ l7) << 3);

#define BAR asm volatile("s_barrier" ::: "memory")
#define LGKM0 asm volatile("s_waitcnt lgkmcnt(0)" ::: "memory")

  // Prologue: A(0), B(0), A(1)h0, B(1) = 14 loads; vmcnt(6) leaves
  // A(1)h0 + B(1) = 6 in flight = steady-state invariant.
  STAGE_A(0, 0, 0); STAGE_A(0, 1, 0);
  STAGE_B(0, 0, 0); STAGE_B(0, 1, 0);
  STAGE_A(1, 0, 1);
  STAGE_B(1, 0, 1); STAGE_B(1, 1, 1);
  asm volatile("s_waitcnt vmcnt(6)" ::: "memory");
  BAR;

  s16x8 aLo[2][4], aHi[2][4], bLo[4], bHi[4];

#pragma unroll 2
  for (int j = 0; j < 20; ++j) {
    const int d = j & 1;
    const int b3 = j % 3;            // B read buffer
    const int bs3 = (j + 2) % 3;     // B stage buffer (tile j+2)

    // ---- phase 0: frags (mf0-1, nf0). reads aLo(8) + bLo(4); stage As[d^1][1].
#pragma unroll
    for (int mf = 0; mf < 2; ++mf)
#pragma unroll
      for (int kf = 0; kf < 4; ++kf)
        aLo[mf][kf] = *(const s16x8*)&As[d][wr][mf * 32 + l31][kslot[kf]];
#pragma unroll
    for (int kf = 0; kf < 4; ++kf)
      bLo[kf] = *(const s16x8*)&Bs[b3][hb][nloc + l31][kslot[kf]];
    if (j < 19) STAGE_A(d ^ 1, 1, j + 1);
    BAR; LGKM0;
    __builtin_amdgcn_s_setprio(1);
#pragma unroll
    for (int kf = 0; kf < 4; ++kf)
#pragma unroll
      for (int mf = 0; mf < 2; ++mf)
        acc[mf][0] = __builtin_amdgcn_mfma_f32_32x32x16_bf16(
            aLo[mf][kf], bLo[kf], acc[mf][0], 0, 0, 0);
    __builtin_amdgcn_s_setprio(0);
    BAR;

    // ---- phase 1: frags (mf0-1, nf1). reads bHi(4); stage Bs[(j+2)%3][0].
#pragma unroll
    for (int kf = 0; kf < 4; ++kf)
      bHi[kf] = *(const s16x8*)&Bs[b3][hb][nloc + 32 + l31][kslot[kf]];
    if (j < 18) STAGE_B(bs3, 0, j + 2);
    BAR; LGKM0;
    __builtin_amdgcn_s_setprio(1);
#pragma unroll
    for (int kf = 0; kf < 4; ++kf)
#pragma unroll
      for (int mf = 0; mf < 2; ++mf)
        acc[mf][1] = __builtin_amdgcn_mfma_f32_32x32x16_bf16(
            aLo[mf][kf], bHi[kf], acc[mf][1], 0, 0, 0);
    __builtin_amdgcn_s_setprio(0);
    BAR;

    // ---- phase 2: frags (mf2-3, nf1). reads aHi(8); stage Bs[(j+2)%3][1].
#pragma unroll
    for (int mf = 0; mf < 2; ++mf)
#pragma unroll
      for (int kf = 0; kf < 4; ++kf)
        aHi[mf][kf] = *(const s16x8*)&As[d][wr][(mf + 2) * 32 + l31][kslot[kf]];
    if (j < 18) STAGE_B(bs3, 1, j + 2);
    BAR; LGKM0;
    __builtin_amdgcn_s_setprio(1);
#pragma unroll
    for (int kf = 0; kf < 4; ++kf)
#pragma unroll
      for (int mf = 0; mf < 2; ++mf)
        acc[mf + 2][1] = __builtin_amdgcn_mfma_f32_32x32x16_bf16(
            aHi[mf][kf], bHi[kf], acc[mf + 2][1], 0, 0, 0);
    __builtin_amdgcn_s_setprio(0);
    BAR;

    // ---- phase 3: frags (mf2-3, nf0). stage As[d][0] (tile j+2); vmcnt(6)
    // BEFORE the tile barrier drains exactly A(j+1)+B(j+1) (>=4 phases old).
    if (j < 18) STAGE_A(d, 0, j + 2);
    BAR;
    __builtin_amdgcn_s_setprio(1);
#pragma unroll
    for (int kf = 0; kf < 4; ++kf)
#pragma unroll
      for (int mf = 0; mf < 2; ++mf)
        acc[mf + 2][0] = __builtin_amdgcn_mfma_f32_32x32x16_bf16(
            aHi[mf][kf], bLo[kf], acc[mf + 2][0], 0, 0, 0);
    __builtin_amdgcn_s_setprio(0);
    if (j <= 17)      asm volatile("s_waitcnt vmcnt(6)" ::: "memory");
    else if (j == 18) asm volatile("s_waitcnt vmcnt(0)" ::: "memory");
    BAR;
  }
#undef STAGE_A
#undef STAGE_B
#undef BAR
#undef LGKM0

  // C/D layout (32x32): col = lane&31, row = (reg&3) + 8*(reg>>2) + 4*(lane>>5)
  const int orow = (lane >> 5) << 2;
  const int ocol = lane & 31;
#pragma unroll
  for (int mf = 0; mf < 4; ++mf) {
#pragma unroll
    for (int nf = 0; nf < 2; ++nf) {
#pragma unroll
      for (int reg = 0; reg < 16; ++reg) {
        const int row = mbase + wr * 128 + mf * 32 + (reg & 3) + ((reg >> 2) << 3) + orow;
        const int col = nbase + wc * 64 + nf * 32 + ocol;
        out[(size_t)row * D_IN + col] = acc[mf][nf][reg];
      }
    }
  }
}

// ---------------- fallback GEMM (R2 structure, fused f32->bf16 A) ----------
__global__ __launch_bounds__(256) void gemm_fb_kernel(const float* __restrict__ x,
                                                      const unsigned short* __restrict__ filt,
                                                      float* __restrict__ out) {
  __shared__ short As[128][32];
  __shared__ short Bs[128][32];

  const int t = threadIdx.x;
  const int lane = t & 63;
  const int wave = t >> 6;
  const int wr = wave >> 1;
  const int wc = wave & 1;

  const int nwg = gridDim.x;
  const int bid = blockIdx.x;
  const int wg = (bid & 7) * (nwg >> 3) + (bid >> 3);
  const int mt = wg / 10;
  const int nt = wg % 10;
  const int mbase = mt * 128;
  const int nbase = nt * 128;

  f32x4 acc[4][4];
#pragma unroll
  for (int m = 0; m < 4; ++m)
#pragma unroll
    for (int n = 0; n < 4; ++n) acc[m][n] = 0.0f;

  const int ar = t >> 1;
  const int ac = (t & 1) << 4;
  const float* __restrict__ asrc = x + (size_t)(mbase + ar) * D_IN + ac;

  const int br = t >> 2;
  const int bc = (t & 3) << 3;
  const unsigned short* __restrict__ bsrc0 = filt + (size_t)(nbase + br) * D_IN + bc;
  const unsigned short* __restrict__ bsrc1 = filt + (size_t)(nbase + br + 64) * D_IN + bc;
  short* bdst0 = &Bs[br][bc];
  short* bdst1 = &Bs[br + 64][bc];

  const int lr = lane & 15;
  const int lk = (lane >> 4) << 3;

  for (int kt = 0; kt < D_IN; kt += 32) {
    gload_lds16(bsrc0 + kt, bdst0);
    gload_lds16(bsrc1 + kt, bdst1);

    const float* src = asrc + kt;
    float4 f0 = *(const float4*)(src + 0);
    float4 f1 = *(const float4*)(src + 4);
    float4 f2 = *(const float4*)(src + 8);
    float4 f3 = *(const float4*)(src + 12);
    u32x4 p0, p1;
    p0[0] = cvtpk(f0.x, f0.y); p0[1] = cvtpk(f0.z, f0.w);
    p0[2] = cvtpk(f1.x, f1.y); p0[3] = cvtpk(f1.z, f1.w);
    p1[0] = cvtpk(f2.x, f2.y); p1[1] = cvtpk(f2.z, f2.w);
    p1[2] = cvtpk(f3.x, f3.y); p1[3] = cvtpk(f3.z, f3.w);
    *(u32x4*)&As[ar][ac] = p0;
    *(u32x4*)&As[ar][ac + 16] = p1;

    __syncthreads();

    s16x8 a[4], b[4];
#pragma unroll
    for (int m = 0; m < 4; ++m)
      a[m] = *(const s16x8*)&As[wr * 64 + m * 16 + lr][lk];
#pragma unroll
    for (int n = 0; n < 4; ++n)
      b[n] = *(const s16x8*)&Bs[wc * 64 + n * 16 + lr][lk];
#pragma unroll
    for (int m = 0; m < 4; ++m)
#pragma unroll
      for (int n = 0; n < 4; ++n)
        acc[m][n] = __builtin_amdgcn_mfma_f32_16x16x32_bf16(a[m], b[n], acc[m][n], 0, 0, 0);

    __syncthreads();
  }

  const int orow = (lane >> 4) << 2;
  const int ocol = lane & 15;
#pragma unroll
  for (int m = 0; m < 4; ++m) {
#pragma unroll
    for (int r = 0; r < 4; ++r) {
      float* cp = out + (size_t)(mbase + wr * 64 + m * 16 + orow + r) * D_IN +
                  nbase + wc * 64 + ocol;
#pragma unroll
      for (int n = 0; n < 4; ++n) cp[n * 16] = acc[m][n][r];
    }
  }
}

extern "C" void kernel_launch(void* const* d_in, const int* in_sizes, int n_in,
                              void* d_out, int out_size, void* d_ws, size_t ws_size,
                              hipStream_t stream) {
  (void)in_sizes; (void)n_in; (void)out_size;
  const float* x = (const float*)d_in[0];
  const float* k1 = (const float*)d_in[1];
  const float* k2 = (const float*)d_in[2];
  const float* k3 = (const float*)d_in[3];
  const float* W = (const float*)d_in[4];
  float* out = (float*)d_out;

  // ws layout: [8KB,+3.28MB) filt bf16; [4MB,+83.9MB) xb bf16 (fast path).
  unsigned short* filt = (unsigned short*)((char*)d_ws + 8192);
  unsigned short* xb = (unsigned short*)((char*)d_ws + (4u << 20));
  const size_t need = (4ull << 20) + (size_t)32768 * D_IN * 2;

  if (ws_size >= need) {
    prep_kernel<<<2368, 320, 0, stream>>>(k1, k2, k3, W, x, filt, xb);
    gemm8p_kernel<<<640, 512, 0, stream>>>(xb, filt, out);
  } else {
    prep_kernel<<<320, 320, 0, stream>>>(k1, k2, k3, W, x, filt, xb);
    gemm_fb_kernel<<<2560, 256, 0, stream>>>(x, filt, out);
  }
}

// Round 16
// 226.693 us; speedup vs baseline: 1.0583x; 1.0583x over previous
//
#include <hip/hip_runtime.h>
#include <stdint.h>

#define D_IN 1280
#define FROWS 4

typedef __attribute__((ext_vector_type(8))) short s16x8;
typedef __attribute__((ext_vector_type(4))) float f32x4;
typedef __attribute__((ext_vector_type(4))) unsigned int u32x4;

__device__ __forceinline__ unsigned short f2bf(float f) {
  union { float f; unsigned u; } v;
  v.f = f;
  unsigned u = v.u;
  return (unsigned short)((u + 0x7fffu + ((u >> 16) & 1u)) >> 16);  // RNE
}

__device__ __forceinline__ unsigned int cvtpk(float lo, float hi) {
  unsigned int r;
  asm("v_cvt_pk_bf16_f32 %0, %1, %2" : "=v"(r) : "v"(lo), "v"(hi));
  return r;
}

__device__ __forceinline__ void gload_lds16(const void* g, void* l) {
  __builtin_amdgcn_global_load_lds(
      (const __attribute__((address_space(1))) void*)g,
      (__attribute__((address_space(3))) void*)l, 16, 0, 0);
}

// ---------------- prep: fused {cayley+filt | cvt} (R11-verified) -----------
__global__ __launch_bounds__(320) void prep_kernel(
    const float* __restrict__ A1, const float* __restrict__ A2,
    const float* __restrict__ A3, const float* __restrict__ W,
    const float* __restrict__ x, unsigned short* __restrict__ filt,
    unsigned short* __restrict__ xb) {
  __shared__ __align__(16) char smem[69632];
  const int bid = blockIdx.x;
  const int t = threadIdx.x;

  if (bid >= 320) {
    const size_t stride = (size_t)2048 * 320 * 8;
    size_t i = ((size_t)(bid - 320) * 320 + t) * 8;
#pragma unroll
    for (int it = 0; it < 8; ++it, i += stride) {
      float4 a = *(const float4*)(x + i);
      float4 b = *(const float4*)(x + i + 4);
      u32x4 p;
      p[0] = cvtpk(a.x, a.y); p[1] = cvtpk(a.z, a.w);
      p[2] = cvtpk(b.x, b.y); p[3] = cvtpk(b.z, b.w);
      *(u32x4*)(xb + i) = p;
    }
    return;
  }

  float (*wS)[D_IN]  = (float (*)[D_IN])(smem);
  float (*t1S)[D_IN] = (float (*)[D_IN])(smem + 20480);
  float (*t2S)[D_IN] = (float (*)[D_IN])(smem + 40960);
  float (*augS)[80]  = (float (*)[80])(smem + 40960);
  float (*NmS)[40]   = (float (*)[40])(smem + 53760);
  float* facS        = (float*)(smem + 60160);
  float* q1S         = (float*)(smem + 61440);
  float* q2S         = (float*)(smem + 61504);
  float* q3S         = (float*)(smem + 61760);

  const int ob = bid * FROWS;

  for (int k = t; k < FROWS * 320; k += 320) {
    int r = k / 320, c = k % 320;
    ((float4*)wS[r])[c] = ((const float4*)(W + (size_t)(ob + r) * D_IN))[c];
  }

  for (int which = 0; which < 3; ++which) {
    const float* __restrict__ A = which == 0 ? A1 : (which == 1 ? A2 : A3);
    float* qd = which == 0 ? q1S : (which == 1 ? q2S : q3S);
    const int n = which == 0 ? 4 : (which == 1 ? 8 : 40);

    for (int idx = t; idx < n * n; idx += 320) {
      int i = idx / n, j = idx % n;
      float s = 0.5f * (A[i * n + j] - A[j * n + i]);
      float eye = (i == j) ? 1.0f : 0.0f;
      augS[i][j] = eye + s;
      augS[i][n + j] = eye;
      NmS[i][j] = eye - s;
    }
    __syncthreads();

    for (int p = 0; p < n; ++p) {
      const float dv = augS[p][p];
      if (t < n) facS[t] = (t == p) ? 0.0f : augS[t][p];
      __syncthreads();
      const float inv = 1.0f / dv;
      if (t < 2 * n) augS[p][t] *= inv;
      __syncthreads();
      for (int idx = t; idx < n * 2 * n; idx += 320) {
        int i = idx / (2 * n), j = idx % (2 * n);
        augS[i][j] -= facS[i] * augS[p][j];
      }
      __syncthreads();
    }

    for (int idx = t; idx < n * n; idx += 320) {
      int i = idx / n, j = idx % n;
      float acc = 0.0f;
      for (int k = 0; k < n; ++k) acc += NmS[i][k] * augS[k][n + j];
      qd[i * n + j] = acc;
    }
    __syncthreads();
  }

  const int i3 = t % 40;
  const int g = t / 40;  // 0..7
  float q3c[40];
#pragma unroll
  for (int j3 = 0; j3 < 40; ++j3) q3c[j3] = q3S[i3 * 40 + j3];
  __syncthreads();

#pragma unroll
  for (int kk = 0; kk < 16; ++kk) {
    const int item = g * 16 + kk;
    const int r = item >> 5;
    const int b = (item & 31) * 40;
    float s = 0.0f;
#pragma unroll
    for (int j3 = 0; j3 < 40; ++j3) s += wS[r][b + j3] * q3c[j3];
    t1S[r][b + i3] = s;
  }
  __syncthreads();

  for (int e = t; e < FROWS * D_IN; e += 320) {
    const int r = e / D_IN;
    const int i = e - r * D_IN;
    const int ii3 = i % 40;
    const int i2 = (i / 40) & 7;
    const int j1 = i / 320;
    float s = 0.0f;
#pragma unroll
    for (int j2 = 0; j2 < 8; ++j2) s += q2S[i2 * 8 + j2] * t1S[r][j1 * 320 + j2 * 40 + ii3];
    t2S[r][i] = s;
  }
  __syncthreads();

  for (int e = t; e < FROWS * D_IN; e += 320) {
    const int r = e / D_IN;
    const int i = e - r * D_IN;
    const int lo = i % 320;
    const int i1 = i / 320;
    float s = 0.0f;
#pragma unroll
    for (int j1 = 0; j1 < 4; ++j1) s += q1S[i1 * 4 + j1] * t2S[r][j1 * 320 + lo];
    filt[(size_t)(ob + r) * D_IN + i] = f2bf(s);
  }
}

// ---------------- main GEMM: 8-phase, 256x256, TRIPLE-BUFFERED B -----------
// R14 kernel, byte-identical (best measured: gemm 136.5 us, MfmaUtil 32,
// FETCH 84.5 MB, 0 bank conflicts; total 226.9 us). 16x16x32 MFMA — the
// 32x32x16 variant measured a structural 4-way LDS read conflict (9.8M,
// R15) because row*128B ≡ bank 0 for all rows; the 16-row fragment read
// of this shape is the conflict-free one.
__global__ __launch_bounds__(512, 1) void gemm8p_kernel(
    const unsigned short* __restrict__ xb,
    const unsigned short* __restrict__ filt,
    float* __restrict__ out) {
  __shared__ short As[2][2][128][64];   // 64 KB
  __shared__ short Bs[3][2][128][64];   // 96 KB

  const int t = threadIdx.x;
  const int lane = t & 63;
  const int wave = t >> 6;
  const int wr = wave >> 2;          // 0..1: M half (128 rows)
  const int wc = wave & 3;           // 0..3: N slice (64 cols)
  const int hb = wc >> 1;            // B half
  const int nloc = (wc & 1) * 64;    // row base within B half

  const int nwg = gridDim.x;         // 640, % 8 == 0
  const int bid = blockIdx.x;
  const int wg = (bid & 7) * (nwg >> 3) + (bid >> 3);  // bijective XCD swizzle
  const int mt = wg / 5;
  const int nt = wg % 5;
  const int mbase = mt * 256;
  const int nbase = nt * 256;

  f32x4 acc[8][4];
#pragma unroll
  for (int m = 0; m < 8; ++m)
#pragma unroll
    for (int n = 0; n < 4; ++n) acc[m][n] = 0.0f;

  const int tr = t >> 3;                        // 0..63
  const int scol = (((t & 7) ^ (tr & 7)) << 3); // source col (elems)
  const int pslot = (t & 7) << 3;               // dest col (elems)
  const unsigned short* __restrict__ abase = xb + (size_t)mbase * D_IN + scol;
  const unsigned short* __restrict__ bbase = filt + (size_t)nbase * D_IN + scol;

#define STAGE_A(P, H, KT)                                                     \
  {                                                                           \
    _Pragma("unroll")                                                         \
    for (int q = 0; q < 2; ++q)                                               \
      gload_lds16(abase + (size_t)((H)*128 + q * 64 + tr) * D_IN + (KT)*64,   \
                  (void*)&As[P][H][q * 64 + tr][pslot]);                      \
  }
#define STAGE_B(P, H, KT)                                                     \
  {                                                                           \
    _Pragma("unroll")                                                         \
    for (int q = 0; q < 2; ++q)                                               \
      gload_lds16(bbase + (size_t)((H)*128 + q * 64 + tr) * D_IN + (KT)*64,   \
                  (void*)&Bs[P][H][q * 64 + tr][pslot]);                      \
  }

  const int lr = lane & 15;
  const int hk = lane >> 4;          // 0..3
  const int c0 = ((hk ^ (lr & 7)) << 3);        // phys col, kk=0 (elems)
  const int c1 = c0 ^ 32;                       // phys col, kk=1

#define BAR asm volatile("s_barrier" ::: "memory")
#define LGKM0 asm volatile("s_waitcnt lgkmcnt(0)" ::: "memory")

  // Prologue: A(0), B(0), A(1)h0, B(1) = 14 loads; vmcnt(6) drains A(0)+B(0),
  // leaving A(1)h0 + B(1) = 6 in flight = the steady-state invariant.
  STAGE_A(0, 0, 0); STAGE_A(0, 1, 0);
  STAGE_B(0, 0, 0); STAGE_B(0, 1, 0);
  STAGE_A(1, 0, 1);
  STAGE_B(1, 0, 1); STAGE_B(1, 1, 1);
  asm volatile("s_waitcnt vmcnt(6)" ::: "memory");
  BAR;

  s16x8 aLo[8], aHi[8], bLo[4], bHi[4];

#pragma unroll 2
  for (int j = 0; j < 20; ++j) {
    const int d = j & 1;
    const int b3 = j % 3;            // B read buffer
    const int bs3 = (j + 2) % 3;     // B stage buffer (tile j+2)

    // ---- phase 0: Q(m0-3, n0-1). reads aLo(8) + bLo(4); stage As[d^1][1].
#pragma unroll
    for (int m = 0; m < 4; ++m) {
      aLo[m * 2 + 0] = *(const s16x8*)&As[d][wr][m * 16 + lr][c0];
      aLo[m * 2 + 1] = *(const s16x8*)&As[d][wr][m * 16 + lr][c1];
    }
#pragma unroll
    for (int n = 0; n < 2; ++n) {
      bLo[n * 2 + 0] = *(const s16x8*)&Bs[b3][hb][nloc + n * 16 + lr][c0];
      bLo[n * 2 + 1] = *(const s16x8*)&Bs[b3][hb][nloc + n * 16 + lr][c1];
    }
    if (j < 19) STAGE_A(d ^ 1, 1, j + 1);
    BAR; LGKM0;
    __builtin_amdgcn_s_setprio(1);
#pragma unroll
    for (int m = 0; m < 4; ++m)
#pragma unroll
      for (int n = 0; n < 2; ++n)
#pragma unroll
        for (int kk = 0; kk < 2; ++kk)
          acc[m][n] = __builtin_amdgcn_mfma_f32_16x16x32_bf16(
              aLo[m * 2 + kk], bLo[n * 2 + kk], acc[m][n], 0, 0, 0);
    __builtin_amdgcn_s_setprio(0);
    BAR;

    // ---- phase 1: Q(m0-3, n2-3). reads bHi(4); stage Bs[(j+2)%3][0].
#pragma unroll
    for (int n = 0; n < 2; ++n) {
      bHi[n * 2 + 0] = *(const s16x8*)&Bs[b3][hb][nloc + (n + 2) * 16 + lr][c0];
      bHi[n * 2 + 1] = *(const s16x8*)&Bs[b3][hb][nloc + (n + 2) * 16 + lr][c1];
    }
    if (j < 18) STAGE_B(bs3, 0, j + 2);
    BAR; LGKM0;
    __builtin_amdgcn_s_setprio(1);
#pragma unroll
    for (int m = 0; m < 4; ++m)
#pragma unroll
      for (int n = 0; n < 2; ++n)
#pragma unroll
        for (int kk = 0; kk < 2; ++kk)
          acc[m][n + 2] = __builtin_amdgcn_mfma_f32_16x16x32_bf16(
              aLo[m * 2 + kk], bHi[n * 2 + kk], acc[m][n + 2], 0, 0, 0);
    __builtin_amdgcn_s_setprio(0);
    BAR;

    // ---- phase 2: Q(m4-7, n2-3). reads aHi(8); stage Bs[(j+2)%3][1].
#pragma unroll
    for (int m = 0; m < 4; ++m) {
      aHi[m * 2 + 0] = *(const s16x8*)&As[d][wr][(m + 4) * 16 + lr][c0];
      aHi[m * 2 + 1] = *(const s16x8*)&As[d][wr][(m + 4) * 16 + lr][c1];
    }
    if (j < 18) STAGE_B(bs3, 1, j + 2);
    BAR; LGKM0;
    __builtin_amdgcn_s_setprio(1);
#pragma unroll
    for (int m = 0; m < 4; ++m)
#pragma unroll
      for (int n = 0; n < 2; ++n)
#pragma unroll
        for (int kk = 0; kk < 2; ++kk)
          acc[m + 4][n + 2] = __builtin_amdgcn_mfma_f32_16x16x32_bf16(
              aHi[m * 2 + kk], bHi[n * 2 + kk], acc[m + 4][n + 2], 0, 0, 0);
    __builtin_amdgcn_s_setprio(0);
    BAR;

    // ---- phase 3: Q(m4-7, n0-1). stage As[d][0] (tile j+2); vmcnt(6)
    // BEFORE the tile barrier drains exactly A(j+1)+B(j+1) (>=4 phases old),
    // leaving B(j+2)+A(j+2)h0 = 6 in flight across the barrier.
    if (j < 18) STAGE_A(d, 0, j + 2);
    BAR;
    __builtin_amdgcn_s_setprio(1);
#pragma unroll
    for (int m = 0; m < 4; ++m)
#pragma unroll
      for (int n = 0; n < 2; ++n)
#pragma unroll
        for (int kk = 0; kk < 2; ++kk)
          acc[m + 4][n] = __builtin_amdgcn_mfma_f32_16x16x32_bf16(
              aHi[m * 2 + kk], bLo[n * 2 + kk], acc[m + 4][n], 0, 0, 0);
    __builtin_amdgcn_s_setprio(0);
    if (j <= 17)      asm volatile("s_waitcnt vmcnt(6)" ::: "memory");
    else if (j == 18) asm volatile("s_waitcnt vmcnt(0)" ::: "memory");
    BAR;
  }
#undef STAGE_A
#undef STAGE_B
#undef BAR
#undef LGKM0

  // C/D layout: col = lane&15, row = (lane>>4)*4 + reg
  const int orow = (lane >> 4) << 2;
  const int ocol = lane & 15;
#pragma unroll
  for (int m = 0; m < 8; ++m) {
#pragma unroll
    for (int r = 0; r < 4; ++r) {
      float* cp = out + (size_t)(mbase + wr * 128 + m * 16 + orow + r) * D_IN +
                  nbase + wc * 64 + ocol;
#pragma unroll
      for (int n = 0; n < 4; ++n) cp[n * 16] = acc[m][n][r];
    }
  }
}

// ---------------- fallback GEMM (R2 structure, fused f32->bf16 A) ----------
__global__ __launch_bounds__(256) void gemm_fb_kernel(const float* __restrict__ x,
                                                      const unsigned short* __restrict__ filt,
                                                      float* __restrict__ out) {
  __shared__ short As[128][32];
  __shared__ short Bs[128][32];

  const int t = threadIdx.x;
  const int lane = t & 63;
  const int wave = t >> 6;
  const int wr = wave >> 1;
  const int wc = wave & 1;

  const int nwg = gridDim.x;
  const int bid = blockIdx.x;
  const int wg = (bid & 7) * (nwg >> 3) + (bid >> 3);
  const int mt = wg / 10;
  const int nt = wg % 10;
  const int mbase = mt * 128;
  const int nbase = nt * 128;

  f32x4 acc[4][4];
#pragma unroll
  for (int m = 0; m < 4; ++m)
#pragma unroll
    for (int n = 0; n < 4; ++n) acc[m][n] = 0.0f;

  const int ar = t >> 1;
  const int ac = (t & 1) << 4;
  const float* __restrict__ asrc = x + (size_t)(mbase + ar) * D_IN + ac;

  const int br = t >> 2;
  const int bc = (t & 3) << 3;
  const unsigned short* __restrict__ bsrc0 = filt + (size_t)(nbase + br) * D_IN + bc;
  const unsigned short* __restrict__ bsrc1 = filt + (size_t)(nbase + br + 64) * D_IN + bc;
  short* bdst0 = &Bs[br][bc];
  short* bdst1 = &Bs[br + 64][bc];

  const int lr = lane & 15;
  const int lk = (lane >> 4) << 3;

  for (int kt = 0; kt < D_IN; kt += 32) {
    gload_lds16(bsrc0 + kt, bdst0);
    gload_lds16(bsrc1 + kt, bdst1);

    const float* src = asrc + kt;
    float4 f0 = *(const float4*)(src + 0);
    float4 f1 = *(const float4*)(src + 4);
    float4 f2 = *(const float4*)(src + 8);
    float4 f3 = *(const float4*)(src + 12);
    u32x4 p0, p1;
    p0[0] = cvtpk(f0.x, f0.y); p0[1] = cvtpk(f0.z, f0.w);
    p0[2] = cvtpk(f1.x, f1.y); p0[3] = cvtpk(f1.z, f1.w);
    p1[0] = cvtpk(f2.x, f2.y); p1[1] = cvtpk(f2.z, f2.w);
    p1[2] = cvtpk(f3.x, f3.y); p1[3] = cvtpk(f3.z, f3.w);
    *(u32x4*)&As[ar][ac] = p0;
    *(u32x4*)&As[ar][ac + 16] = p1;

    __syncthreads();

    s16x8 a[4], b[4];
#pragma unroll
    for (int m = 0; m < 4; ++m)
      a[m] = *(const s16x8*)&As[wr * 64 + m * 16 + lr][lk];
#pragma unroll
    for (int n = 0; n < 4; ++n)
      b[n] = *(const s16x8*)&Bs[wc * 64 + n * 16 + lr][lk];
#pragma unroll
    for (int m = 0; m < 4; ++m)
#pragma unroll
      for (int n = 0; n < 4; ++n)
        acc[m][n] = __builtin_amdgcn_mfma_f32_16x16x32_bf16(a[m], b[n], acc[m][n], 0, 0, 0);

    __syncthreads();
  }

  const int orow = (lane >> 4) << 2;
  const int ocol = lane & 15;
#pragma unroll
  for (int m = 0; m < 4; ++m) {
#pragma unroll
    for (int r = 0; r < 4; ++r) {
      float* cp = out + (size_t)(mbase + wr * 64 + m * 16 + orow + r) * D_IN +
                  nbase + wc * 64 + ocol;
#pragma unroll
      for (int n = 0; n < 4; ++n) cp[n * 16] = acc[m][n][r];
    }
  }
}

extern "C" void kernel_launch(void* const* d_in, const int* in_sizes, int n_in,
                              void* d_out, int out_size, void* d_ws, size_t ws_size,
                              hipStream_t stream) {
  (void)in_sizes; (void)n_in; (void)out_size;
  const float* x = (const float*)d_in[0];
  const float* k1 = (const float*)d_in[1];
  const float* k2 = (const float*)d_in[2];
  const float* k3 = (const float*)d_in[3];
  const float* W = (const float*)d_in[4];
  float* out = (float*)d_out;

  // ws layout: [8KB,+3.28MB) filt bf16; [4MB,+83.9MB) xb bf16 (fast path).
  unsigned short* filt = (unsigned short*)((char*)d_ws + 8192);
  unsigned short* xb = (unsigned short*)((char*)d_ws + (4u << 20));
  const size_t need = (4ull << 20) + (size_t)32768 * D_IN * 2;

  if (ws_size >= need) {
    prep_kernel<<<2368, 320, 0, stream>>>(k1, k2, k3, W, x, filt, xb);
    gemm8p_kernel<<<640, 512, 0, stream>>>(xb, filt, out);
  } else {
    prep_kernel<<<320, 320, 0, stream>>>(k1, k2, k3, W, x, filt, xb);
    gemm_fb_kernel<<<2560, 256, 0, stream>>>(x, filt, out);
  }
}